// Round 10
// baseline (736.912 us; speedup 1.0000x reference)
//
#include <hip/hip_runtime.h>
#include <hip/hip_cooperative_groups.h>
#include <cstdint>

namespace cg = cooperative_groups;

#define F 64
#define TILE1 8192     // edges per bucketing tile
#define MAXFB 1024     // max fine buckets (supports N <= 131072)
#define SCAN_BLK 1024  // elements per scan chunk (nbScan must stay <= 256)
#define ECAP 2048      // staged edge capacity per bucket (mean 1536, 13 sigma)
#define PRE_BLOCKS 256
#define PRE_THREADS 1024

typedef short bf16x8 __attribute__((ext_vector_type(8)));
typedef float f32x4  __attribute__((ext_vector_type(4)));

// ---------------------------------------------------------------------------
// bf16 helpers
// ---------------------------------------------------------------------------
__device__ __forceinline__ unsigned short f2b(float f) {     // RNE round
    unsigned u = __float_as_uint(f);
    unsigned r = u + 0x7fffu + ((u >> 16) & 1u);
    return (unsigned short)(r >> 16);
}
__device__ __forceinline__ void add8(float* a, uint4 u) {
    const unsigned* p = (const unsigned*)&u;
#pragma unroll
    for (int i = 0; i < 4; ++i) {
        a[2 * i + 0] += __uint_as_float(p[i] << 16);
        a[2 * i + 1] += __uint_as_float(p[i] & 0xffff0000u);
    }
}

// ---------------------------------------------------------------------------
// Device helper: weight B-fragment packing (shared by coop + classic paths)
// ---------------------------------------------------------------------------
__device__ __forceinline__ void pack_weight_frag(
    int g, const float* Wl0, const float* Wr0, const float* Wl1,
    const float* Wr1, const float* Wl2, const float* Wr2, ushort* wbuf) {
    int set = g >> 10;
    int fl = g & 1023;
    int f = fl >> 6;              // frag id = s*4+ot
    int l = fl & 63;
    int s = f >> 2;
    int ot = f & 3;
    const float* Wl = (set == 0) ? Wl0 : (set == 1) ? Wl1 : Wl2;
    const float* Wr = (set == 0) ? Wr0 : (set == 1) ? Wr1 : Wr2;
    int o = ot * 16 + (l & 15);
    int k0 = s * 32 + (l >> 4) * 8;
    unsigned d[4];
#pragma unroll
    for (int p = 0; p < 4; ++p) {
        int ka = k0 + 2 * p, kb = k0 + 2 * p + 1;
        float va = (ka < 64) ? Wl[o * 64 + ka] : Wr[o * 64 + (ka - 64)];
        float vb = (kb < 64) ? Wl[o * 64 + kb] : Wr[o * 64 + (kb - 64)];
        d[p] = (unsigned)f2b(va) | ((unsigned)f2b(vb) << 16);
    }
    ((uint4*)wbuf)[g] = make_uint4(d[0], d[1], d[2], d[3]);
}

// ---------------------------------------------------------------------------
// pre_coop: ONE cooperative kernel for all preprocessing, using the PROVEN
// round-7 algorithms (LDS hist, chunk scan, LDS-cursor scatter, counting-sort
// phase2 + degree-rank perm). Grid 256 x 1024 — same safe shape that launched
// fine in round 2. Launch return code is CHECKED host-side; classic pipeline
// is the fallback.
// ---------------------------------------------------------------------------
__global__ __launch_bounds__(PRE_THREADS, 4) void pre_coop(
    const float* __restrict__ Wl0, const float* __restrict__ Wr0,
    const float* __restrict__ Wl1, const float* __restrict__ Wr1,
    const float* __restrict__ Wl2, const float* __restrict__ Wr2,
    ushort* __restrict__ wbuf,
    const float* __restrict__ x, ushort* __restrict__ xb, int nElem,
    const int* __restrict__ src, const int* __restrict__ dst,
    int* __restrict__ binMat, int* __restrict__ blockSums,
    unsigned* __restrict__ stage2, int* __restrict__ csrSrc,
    int* __restrict__ rowStart, int* __restrict__ perm,
    int E, int NB1, int nf, int scanLen, int nbScan) {
    cg::grid_group grid = cg::this_grid();
    __shared__ int shmem[PRE_THREADS];          // reused by every phase

    const int t = threadIdx.x;
    const int b = blockIdx.x;
    const int gid = b * PRE_THREADS + t;
    const int GT = PRE_BLOCKS * PRE_THREADS;

    // ---- P0a: weight fragments (first 3072 threads) ----
    if (gid < 3072) pack_weight_frag(gid, Wl0, Wr0, Wl1, Wr1, Wl2, Wr2, wbuf);

    // ---- P0b: x -> bf16 (grid-stride float4) ----
    {
        int n4 = nElem >> 2;
        const float4* x4 = (const float4*)x;
        for (int i = gid; i < n4; i += GT) {
            float4 v = x4[i];
            uint2 o;
            o.x = (unsigned)f2b(v.x) | ((unsigned)f2b(v.y) << 16);
            o.y = (unsigned)f2b(v.z) | ((unsigned)f2b(v.w) << 16);
            ((uint2*)xb)[i] = o;
        }
    }
    // ---- P0c: per-tile histogram (LDS atomics), tiles grid-stride ----
    for (int tb = b; tb < NB1; tb += gridDim.x) {
        for (int i = t; i < nf; i += PRE_THREADS) shmem[i] = 0;
        __syncthreads();
        int base = tb * TILE1;
        int end = min(base + TILE1, E);
        const int4* d4 = (const int4*)dst;
        int n4 = (end - base) >> 2;
        int b4 = base >> 2;
        for (int k = t; k < n4; k += PRE_THREADS) {
            int4 v = d4[b4 + k];
            atomicAdd(&shmem[v.x >> 7], 1);
            atomicAdd(&shmem[v.y >> 7], 1);
            atomicAdd(&shmem[v.z >> 7], 1);
            atomicAdd(&shmem[v.w >> 7], 1);
        }
        __syncthreads();
        for (int i = t; i < nf; i += PRE_THREADS) binMat[i * NB1 + tb] = shmem[i];
        __syncthreads();
    }
    __threadfence();
    grid.sync();

    // ---- P1: per-chunk exclusive scan (block b handles chunk b) ----
    {
        int i = b * PRE_THREADS + t;
        int v = (b < nbScan && i < scanLen) ? binMat[i] : 0;
        shmem[t] = v;
        __syncthreads();
        for (int off = 1; off < PRE_THREADS; off <<= 1) {
            int add = (t >= off) ? shmem[t - off] : 0;
            __syncthreads();
            shmem[t] += add;
            __syncthreads();
        }
        int incl = shmem[t];
        if (b < nbScan && i < scanLen) binMat[i] = incl - v;
        if (b < nbScan && t == PRE_THREADS - 1) blockSums[b] = incl;
    }
    __threadfence();
    grid.sync();

    // ---- P2: block 0 exclusive-scans the chunk sums (in place) ----
    if (b == 0) {
        int v = (t < nbScan) ? blockSums[t] : 0;
        shmem[t] = v;
        __syncthreads();
        for (int off = 1; off < PRE_THREADS; off <<= 1) {
            int add = (t >= off) ? shmem[t - off] : 0;
            __syncthreads();
            shmem[t] += add;
            __syncthreads();
        }
        if (t < nbScan) blockSums[t] = shmem[t] - v;
    }
    __threadfence();
    grid.sync();

    // ---- P4: scatter -> stage2 (deterministic, LDS cursors) ----
    for (int tb = b; tb < NB1; tb += gridDim.x) {
        for (int i = t; i < nf; i += PRE_THREADS) {
            int j = i * NB1 + tb;
            shmem[i] = binMat[j] + blockSums[j >> 10];
        }
        __syncthreads();
        int base = tb * TILE1;
        int end = min(base + TILE1, E);
        const int4* s4 = (const int4*)src;
        const int4* d4 = (const int4*)dst;
        int n4 = (end - base) >> 2;
        int b4 = base >> 2;
        for (int k = t; k < n4; k += PRE_THREADS) {
            int4 s = s4[b4 + k];
            int4 d = d4[b4 + k];
            int p0 = atomicAdd(&shmem[d.x >> 7], 1);
            int p1 = atomicAdd(&shmem[d.y >> 7], 1);
            int p2 = atomicAdd(&shmem[d.z >> 7], 1);
            int p3 = atomicAdd(&shmem[d.w >> 7], 1);
            stage2[p0] = ((unsigned)(d.x & 127) << 17) | (unsigned)s.x;
            stage2[p1] = ((unsigned)(d.y & 127) << 17) | (unsigned)s.y;
            stage2[p2] = ((unsigned)(d.z & 127) << 17) | (unsigned)s.z;
            stage2[p3] = ((unsigned)(d.w & 127) << 17) | (unsigned)s.w;
        }
        __syncthreads();
    }
    __threadfence();
    grid.sync();

    // ---- P5: phase2 -> csrSrc + rowStart + perm (grid-stride buckets) ----
    {
        int* cnt   = shmem;              // 128
        int* pre   = shmem + 128;        // 129
        int* curb  = shmem + 272;        // 128
        int* permL = shmem + 416;        // 128
        for (int bk = b; bk < nf; bk += gridDim.x) {
            int j0 = bk * NB1;
            int s = binMat[j0] + blockSums[j0 >> 10];
            int e2 = E;
            if (bk + 1 < nf) {
                int j1 = (bk + 1) * NB1;
                e2 = binMat[j1] + blockSums[j1 >> 10];
            }
            if (t < 128) cnt[t] = 0;
            __syncthreads();
            for (int i = s + t; i < e2; i += PRE_THREADS)
                atomicAdd(&cnt[(stage2[i] >> 17) & 127], 1);
            __syncthreads();
            if (t < 128) pre[t + 1] = cnt[t];
            if (t == 0) pre[0] = 0;
            // degree rank (stable: desc degree, asc index)
            if (t < 128) {
                int my = cnt[t];
                int r = 0;
                for (int j = 0; j < 128; ++j) {
                    int cj = cnt[j];
                    r += (cj > my) || (cj == my && j < t);
                }
                permL[r] = t;
            }
            __syncthreads();
            for (int off = 1; off < 128; off <<= 1) {
                int v = 0;
                if (t < 128 && (t + 1) > off) v = pre[t + 1 - off];
                __syncthreads();
                if (t < 128 && (t + 1) > off) pre[t + 1] += v;
                __syncthreads();
            }
            if (t < 128) curb[t] = pre[t];
            if (t < 129) rowStart[bk * 128 + t] = s + pre[t];
            if (t < 128) perm[bk * 128 + t] = permL[t];
            __syncthreads();
            for (int i = s + t; i < e2; i += PRE_THREADS) {
                unsigned w = stage2[i];
                int pos = atomicAdd(&curb[(w >> 17) & 127], 1);
                csrSrc[s + pos] = (int)(w & 0x1FFFFu);
            }
            __syncthreads();
        }
    }
}

// ---------------------------------------------------------------------------
// CLASSIC FALLBACK PIPELINE (round-7, proven): used only if the cooperative
// launch is rejected at runtime.
// ---------------------------------------------------------------------------
__global__ __launch_bounds__(256) void prep_hist_kernel(
    const float* __restrict__ Wl0, const float* __restrict__ Wr0,
    const float* __restrict__ Wl1, const float* __restrict__ Wr1,
    const float* __restrict__ Wl2, const float* __restrict__ Wr2,
    ushort* __restrict__ wbuf,
    const float* __restrict__ x, ushort* __restrict__ xb, int nElem,
    const int* __restrict__ dst, int* __restrict__ binMat,
    int E, int NB1, int nf) {
    __shared__ int h[MAXFB];
    int b = blockIdx.x;
    int t = threadIdx.x;
    if (b < 12) {
        pack_weight_frag(b * 256 + t, Wl0, Wr0, Wl1, Wr1, Wl2, Wr2, wbuf);
    } else if (b < 12 + NB1) {
        int tb = b - 12;              // tile index
        for (int i = t; i < nf; i += 256) h[i] = 0;
        __syncthreads();
        int base = tb * TILE1;
        int end = min(base + TILE1, E);
        const int4* d4 = (const int4*)dst;
        int n4 = (end - base) >> 2;
        int b4 = base >> 2;
        for (int k = t; k < n4; k += 256) {
            int4 v = d4[b4 + k];
            atomicAdd(&h[v.x >> 7], 1);
            atomicAdd(&h[v.y >> 7], 1);
            atomicAdd(&h[v.z >> 7], 1);
            atomicAdd(&h[v.w >> 7], 1);
        }
        __syncthreads();
        for (int i = t; i < nf; i += 256) binMat[i * NB1 + tb] = h[i];
    } else {
        int i = (b - 12 - NB1) * 256 + t;   // float4 index
        int n4 = nElem >> 2;
        if (i < n4) {
            float4 v = ((const float4*)x)[i];
            uint2 o;
            o.x = (unsigned)f2b(v.x) | ((unsigned)f2b(v.y) << 16);
            o.y = (unsigned)f2b(v.z) | ((unsigned)f2b(v.w) << 16);
            ((uint2*)xb)[i] = o;
        }
    }
}

__global__ __launch_bounds__(SCAN_BLK) void scan_blocks_kernel(
    int* __restrict__ a, int* __restrict__ blockSums, int len) {
    __shared__ int sh[SCAN_BLK];
    int t = threadIdx.x;
    int i = blockIdx.x * SCAN_BLK + t;
    int v = (i < len) ? a[i] : 0;
    sh[t] = v;
    __syncthreads();
    for (int off = 1; off < SCAN_BLK; off <<= 1) {
        int add = (t >= off) ? sh[t - off] : 0;
        __syncthreads();
        sh[t] += add;
        __syncthreads();
    }
    int incl = sh[t];
    if (i < len) a[i] = incl - v;
    if (t == SCAN_BLK - 1) blockSums[blockIdx.x] = incl;   // raw chunk total
}

__device__ __forceinline__ void scan_sums_lds(
    const int* __restrict__ blockSums, int nbScan, int* sBS) {
    int t = threadIdx.x;
    int v = (t < nbScan) ? blockSums[t] : 0;
    sBS[t] = v;
    __syncthreads();
    for (int off = 1; off < 256; off <<= 1) {
        int add = (t >= off) ? sBS[t - off] : 0;
        __syncthreads();
        sBS[t] += add;
        __syncthreads();
    }
    int excl = sBS[t] - v;
    __syncthreads();
    sBS[t] = excl;
    __syncthreads();
}

__global__ __launch_bounds__(256) void scatter_kernel(
    const int* __restrict__ src, const int* __restrict__ dst,
    const int* __restrict__ binMat, const int* __restrict__ blockSums,
    unsigned* __restrict__ stage2, int E, int NB1, int nf, int nbScan) {
    __shared__ int cur[MAXFB];
    __shared__ int sBS[256];
    int t = threadIdx.x;
    scan_sums_lds(blockSums, nbScan, sBS);
    for (int i = t; i < nf; i += 256) {
        int j = i * NB1 + blockIdx.x;
        cur[i] = binMat[j] + sBS[j >> 10];
    }
    __syncthreads();
    int base = blockIdx.x * TILE1;
    int end = min(base + TILE1, E);
    const int4* s4 = (const int4*)src;
    const int4* d4 = (const int4*)dst;
    int n4 = (end - base) >> 2;
    int b4 = base >> 2;
    for (int k = t; k < n4; k += 256) {
        int4 s = s4[b4 + k];
        int4 d = d4[b4 + k];
        int p0 = atomicAdd(&cur[d.x >> 7], 1);
        int p1 = atomicAdd(&cur[d.y >> 7], 1);
        int p2 = atomicAdd(&cur[d.z >> 7], 1);
        int p3 = atomicAdd(&cur[d.w >> 7], 1);
        stage2[p0] = ((unsigned)(d.x & 127) << 17) | (unsigned)s.x;
        stage2[p1] = ((unsigned)(d.y & 127) << 17) | (unsigned)s.y;
        stage2[p2] = ((unsigned)(d.z & 127) << 17) | (unsigned)s.z;
        stage2[p3] = ((unsigned)(d.w & 127) << 17) | (unsigned)s.w;
    }
}

__global__ __launch_bounds__(256) void phase2_kernel(
    const unsigned* __restrict__ stage2, const int* __restrict__ binMat,
    const int* __restrict__ blockSums,
    int* __restrict__ csrSrc, int* __restrict__ rowStart,
    int* __restrict__ perm,
    int E, int NB1, int nf, int nbScan) {
    __shared__ int cnt[128];
    __shared__ int pre[129];
    __shared__ int cur[128];
    __shared__ int sBS[256];
    __shared__ int permL[128];
    int b = blockIdx.x;
    int t = threadIdx.x;
    scan_sums_lds(blockSums, nbScan, sBS);
    int j0 = b * NB1;
    int s = binMat[j0] + sBS[j0 >> 10];
    int e2 = E;
    if (b + 1 < nf) {
        int j1 = (b + 1) * NB1;
        e2 = binMat[j1] + sBS[j1 >> 10];
    }
    if (t < 128) cnt[t] = 0;
    __syncthreads();
    for (int i = s + t; i < e2; i += 256)
        atomicAdd(&cnt[(stage2[i] >> 17) & 127], 1);
    __syncthreads();
    if (t < 128) pre[t + 1] = cnt[t];
    if (t == 0) pre[0] = 0;
    if (t < 128) {
        int my = cnt[t];
        int r = 0;
        for (int j = 0; j < 128; ++j) {
            int cj = cnt[j];
            r += (cj > my) || (cj == my && j < t);
        }
        permL[r] = t;
    }
    __syncthreads();
    for (int off = 1; off < 128; off <<= 1) {
        int v = 0;
        if (t < 128 && (t + 1) > off) v = pre[t + 1 - off];
        __syncthreads();
        if (t < 128 && (t + 1) > off) pre[t + 1] += v;
        __syncthreads();
    }
    if (t < 128) cur[t] = pre[t];
    if (t < 129) rowStart[b * 128 + t] = s + pre[t];
    if (t < 128) perm[b * 128 + t] = permL[t];
    __syncthreads();
    for (int i = s + t; i < e2; i += 256) {
        unsigned w = stage2[i];
        int pos = atomicAdd(&cur[(w >> 17) & 127], 1);
        csrSrc[s + pos] = (int)(w & 0x1FFFFu);
    }
}

// ---------------------------------------------------------------------------
// Fused layer (round-7 proven version; 512 threads = 8 waves per tile):
//   Stage:   bucket's contiguous csrSrc slice -> LDS eidx (coalesced, 8 KB).
//   Phase A: gather, 8 lanes/node, 2 nodes/thread, degree-balanced
//            heavy+light team pairing via perm. csrSrc accumulation order
//            unchanged => bit-identical output.
//   Phase B: MFMA matvec, each wave owns one 16-node m-tile
//   Epilogue: tanh + transpose via reused LDS, two 64-row halves.
// flags: bit0 = tanh, bit1 = bf16 output.
// ---------------------------------------------------------------------------
__global__ __launch_bounds__(512, 4) void fused_layer(
    const ushort* __restrict__ hb, const int* __restrict__ rowStart,
    const int* __restrict__ csrSrc, const int* __restrict__ perm,
    const ushort* __restrict__ wbuf,
    const float* __restrict__ bl, void* __restrict__ out, int n, int flags) {
    __shared__ __align__(16) ushort smem[128 * 72];
    __shared__ int eidx[ECAP];

    int t = threadIdx.x;
    int node0b = blockIdx.x * 128;
    const uint4* h16 = (const uint4*)hb;

    // ---- Stage: bucket edge indices -> LDS (coalesced) ----
    int e0 = rowStart[node0b];
    int ne = rowStart[node0b + 128] - e0;
    bool useL = (ne <= ECAP);
    if (useL) {
        for (int i = t; i < ne; i += 512) eidx[i] = csrSrc[e0 + i];
    }
    __syncthreads();

    // ---- Phase A: gather into LDS ----
    {
        int c = t & 7;                 // 16B feature chunk
        int tm = t >> 3;               // team 0..63
        const int* permB = perm + blockIdx.x * 128;
        int nl0 = permB[tm];           // heavy node
        int nl1 = permB[127 - tm];     // light node

        auto run = [&](auto IDX) {
#pragma unroll 1
            for (int r = 0; r < 2; ++r) {
                int nl = (r == 0) ? nl0 : nl1;
                int node = node0b + nl;
                float a[8] = {0.f, 0.f, 0.f, 0.f, 0.f, 0.f, 0.f, 0.f};
                int e = rowStart[node];
                int end = rowStart[node + 1];
                for (; e + 3 < end; e += 4) {
                    int s0 = IDX(e + 0);
                    int s1 = IDX(e + 1);
                    int s2 = IDX(e + 2);
                    int s3 = IDX(e + 3);
                    uint4 u0 = h16[(size_t)s0 * 8 + c];
                    uint4 u1 = h16[(size_t)s1 * 8 + c];
                    uint4 u2 = h16[(size_t)s2 * 8 + c];
                    uint4 u3 = h16[(size_t)s3 * 8 + c];
                    add8(a, u0); add8(a, u1); add8(a, u2); add8(a, u3);
                }
                for (; e < end; ++e) {
                    uint4 u0 = h16[(size_t)IDX(e) * 8 + c];
                    add8(a, u0);
                }
                unsigned d[4];
#pragma unroll
                for (int p = 0; p < 4; ++p)
                    d[p] = (unsigned)f2b(a[2 * p]) | ((unsigned)f2b(a[2 * p + 1]) << 16);
                *(uint4*)(smem + nl * 72 + c * 8) = make_uint4(d[0], d[1], d[2], d[3]);
            }
        };
        if (useL) run([&](int e) { return eidx[e - e0]; });
        else      run([&](int e) { return csrSrc[e]; });
    }
    __syncthreads();

    // ---- Phase B: MFMA matvec (A from LDS for agg, global for self) ----
    int w = t >> 6;                    // wave 0..7 -> 16-node m-tile
    int l = t & 63;
    int quad = l >> 4;
    int lo = l & 15;

    f32x4 acc[4];
#pragma unroll
    for (int ot = 0; ot < 4; ++ot) {
        float bv = bl[ot * 16 + lo];
        f32x4 bvv = {bv, bv, bv, bv};
        acc[ot] = bvv;
    }

#pragma unroll
    for (int s = 0; s < 4; ++s) {
        bf16x8 A;
        if (s < 2) {
            int nl = w * 16 + lo;
            A = *(const bf16x8*)(smem + nl * 72 + s * 32 + quad * 8);
        } else {
            size_t node = (size_t)node0b + w * 16 + lo;
            A = *(const bf16x8*)(hb + node * 64 + (s & 1) * 32 + quad * 8);
        }
#pragma unroll
        for (int ot = 0; ot < 4; ++ot) {
            bf16x8 B = *(const bf16x8*)(wbuf + (((s * 4 + ot) * 64) + l) * 8);
            acc[ot] = __builtin_amdgcn_mfma_f32_16x16x32_bf16(A, B, acc[ot], 0, 0, 0);
        }
    }
    __syncthreads();               // all aggL reads done; smem becomes outT

    // ---- Epilogue: tanh + transpose via LDS, two 64-row halves ----
    float* outT = (float*)smem;
    int whalf = w >> 2;            // which half this wave's rows belong to
    int wrow = (w & 3) * 16;       // row base within the half

#pragma unroll
    for (int half = 0; half < 2; ++half) {
        if (whalf == half) {
#pragma unroll
            for (int ot = 0; ot < 4; ++ot) {
                f32x4 v = acc[ot];
                if (flags & 1) {
                    v[0] = tanhf(v[0]); v[1] = tanhf(v[1]);
                    v[2] = tanhf(v[2]); v[3] = tanhf(v[3]);
                }
                int row = wrow + quad * 4;
                int col = ot * 16 + lo;
#pragma unroll
                for (int r = 0; r < 4; ++r)
                    outT[(row + r) * 68 + col] = v[r];
            }
        }
        __syncthreads();
        // cooperative store of this half's 64 rows: 8 lanes/row x 8 cols
        int hr = t >> 3;
        int node = node0b + half * 64 + hr;
        if (node < n) {
            const float* srcp = &outT[hr * 68 + (t & 7) * 8];
            if (flags & 2) {
                uint4* o8 = (uint4*)out;     // bf16 row = 8 uint4
                unsigned dd[4];
#pragma unroll
                for (int p = 0; p < 4; ++p) {
                    float va = srcp[2 * p];
                    float vb = srcp[2 * p + 1];
                    dd[p] = (unsigned)f2b(va) | ((unsigned)f2b(vb) << 16);
                }
                o8[(size_t)node * 8 + (t & 7)] = make_uint4(dd[0], dd[1], dd[2], dd[3]);
            } else {
                float4* o16 = (float4*)out;  // fp32 row = 16 float4
#pragma unroll
                for (int q = 0; q < 2; ++q) {
                    float4 v = *(const float4*)(srcp + q * 4);
                    o16[(size_t)node * 16 + (t & 7) * 2 + q] = v;
                }
            }
        }
        if (half == 0) __syncthreads();      // protect outT before half-1 writes
    }
}

// ---------------------------------------------------------------------------
// Launch
// ---------------------------------------------------------------------------
extern "C" void kernel_launch(void* const* d_in, const int* in_sizes, int n_in,
                              void* d_out, int out_size, void* d_ws, size_t ws_size,
                              hipStream_t stream) {
    const float* x      = (const float*)d_in[0];
    const int*   edges  = (const int*)d_in[1];
    const float* Wl_in  = (const float*)d_in[2];
    const float* bl_in  = (const float*)d_in[3];
    const float* Wr_in  = (const float*)d_in[4];
    const float* Wl_med = (const float*)d_in[5];
    const float* bl_med = (const float*)d_in[6];
    const float* Wr_med = (const float*)d_in[7];
    const float* Wl_out = (const float*)d_in[8];
    const float* bl_out = (const float*)d_in[9];
    const float* Wr_out = (const float*)d_in[10];

    const int N = in_sizes[0] / F;
    const int E = in_sizes[1] / 2;
    const int* srcp = edges;
    const int* dstp = edges + E;

    const int nf  = (N + 127) >> 7;              // fine buckets (782)
    const int NB1 = (E + TILE1 - 1) / TILE1;     // bucketing tiles (147)
    const int NR  = nf * 128;                    // padded node count
    const int scanLen = nf * NB1;
    const int nbScan = (scanLen + SCAN_BLK - 1) / SCAN_BLK;   // 113 (<= 256)

    // Workspace layout (16B-aligned chunks)
    ushort*  wbuf      = (ushort*)d_ws;                        // 3*8192 bf16
    ushort*  xb        = wbuf + 3 * 8192;                      // NR*F bf16
    ushort*  hAb       = xb + (size_t)NR * F;                  // NR*F bf16
    ushort*  hBb       = hAb + (size_t)NR * F;                 // NR*F bf16
    int*     rowStart  = (int*)(hBb + (size_t)NR * F);         // NR+2
    int*     blockSums = rowStart + NR + 2;                    // nbScan (<=1024)
    int*     binMat    = blockSums + SCAN_BLK;                 // nf*NB1
    unsigned* stage2   = (unsigned*)(binMat + scanLen);        // E
    int*     csrSrc    = (int*)(stage2 + E);                   // E
    int*     perm      = csrSrc + E;                           // NR

    int nElem = N * F;
    int Ei = E, NB1i = NB1, nfi = nf, sLi = scanLen, nbSi = nbScan;

    void* argsP[] = {
        (void*)&Wl_in, (void*)&Wr_in, (void*)&Wl_med, (void*)&Wr_med,
        (void*)&Wl_out, (void*)&Wr_out, (void*)&wbuf,
        (void*)&x, (void*)&xb, (void*)&nElem,
        (void*)&srcp, (void*)&dstp,
        (void*)&binMat, (void*)&blockSums, (void*)&stage2,
        (void*)&csrSrc, (void*)&rowStart, (void*)&perm,
        (void*)&Ei, (void*)&NB1i, (void*)&nfi, (void*)&sLi, (void*)&nbSi,
    };
    hipError_t cerr = hipLaunchCooperativeKernel(
        pre_coop, dim3(PRE_BLOCKS), dim3(PRE_THREADS), argsP, 0u, stream);

    if (cerr != hipSuccess) {
        // Fallback: classic 4-kernel pipeline (round-7 proven)
        const int prep_blocks = 12 + NB1 + (N * F / 4 + 255) / 256;
        prep_hist_kernel<<<prep_blocks, 256, 0, stream>>>(
            Wl_in, Wr_in, Wl_med, Wr_med, Wl_out, Wr_out, wbuf, x, xb, N * F,
            dstp, binMat, E, NB1, nf);
        scan_blocks_kernel<<<nbScan, SCAN_BLK, 0, stream>>>(binMat, blockSums, scanLen);
        scatter_kernel<<<NB1, 256, 0, stream>>>(srcp, dstp, binMat, blockSums, stage2, E, NB1, nf, nbScan);
        phase2_kernel<<<nf, 256, 0, stream>>>(stage2, binMat, blockSums, csrSrc, rowStart, perm, E, NB1, nf, nbScan);
    }

    // Fused layers: gather + MFMA matvec in one kernel per layer (round-7)
    fused_layer<<<nf, 512, 0, stream>>>(xb,  rowStart, csrSrc, perm, wbuf,         bl_in,  hAb,   N, 3);
    fused_layer<<<nf, 512, 0, stream>>>(hAb, rowStart, csrSrc, perm, wbuf + 8192,  bl_med, hBb,   N, 3);
    fused_layer<<<nf, 512, 0, stream>>>(hBb, rowStart, csrSrc, perm, wbuf + 8192,  bl_med, hAb,   N, 3);
    fused_layer<<<nf, 512, 0, stream>>>(hAb, rowStart, csrSrc, perm, wbuf + 16384, bl_out, d_out, N, 0);
}

// Round 11
// 262.423 us; speedup vs baseline: 2.8081x; 2.8081x over previous
//
#include <hip/hip_runtime.h>
#include <cstdint>

#define F 64
#define TILE1 4096     // edges per bucketing tile (293 tiles -> >1 block/CU for hist+scatter)
#define MAXFB 1024     // max fine buckets (supports N <= 131072)
#define SCAN_BLK 1024  // elements per scan chunk (nbScan must stay <= 256)
#define ECAP 2048      // staged edge capacity per bucket (mean 1536, 13 sigma)

typedef short bf16x8 __attribute__((ext_vector_type(8)));
typedef float f32x4  __attribute__((ext_vector_type(4)));

// ---------------------------------------------------------------------------
// bf16 helpers
// ---------------------------------------------------------------------------
__device__ __forceinline__ unsigned short f2b(float f) {     // RNE round
    unsigned u = __float_as_uint(f);
    unsigned r = u + 0x7fffu + ((u >> 16) & 1u);
    return (unsigned short)(r >> 16);
}
__device__ __forceinline__ void add8(float* a, uint4 u) {
    const unsigned* p = (const unsigned*)&u;
#pragma unroll
    for (int i = 0; i < 4; ++i) {
        a[2 * i + 0] += __uint_as_float(p[i] << 16);
        a[2 * i + 1] += __uint_as_float(p[i] & 0xffff0000u);
    }
}

// ---------------------------------------------------------------------------
// Merged prep + hist:
//   blocks [0,12)           : weight B-fragments -> wbuf
//   blocks [12, 12+NB1)     : per-tile histogram by fine bucket (LDS atomics)
//   blocks [12+NB1, ...)    : x -> bf16
// ---------------------------------------------------------------------------
__global__ __launch_bounds__(256) void prep_hist_kernel(
    const float* __restrict__ Wl0, const float* __restrict__ Wr0,
    const float* __restrict__ Wl1, const float* __restrict__ Wr1,
    const float* __restrict__ Wl2, const float* __restrict__ Wr2,
    ushort* __restrict__ wbuf,
    const float* __restrict__ x, ushort* __restrict__ xb, int nElem,
    const int* __restrict__ dst, int* __restrict__ binMat,
    int E, int NB1, int nf) {
    __shared__ int h[MAXFB];
    int b = blockIdx.x;
    int t = threadIdx.x;
    if (b < 12) {
        int g = b * 256 + t;          // g < 3072 = 3 sets * 16 frags * 64 lanes
        int set = g >> 10;
        int fl = g & 1023;
        int f = fl >> 6;              // frag id = s*4+ot
        int l = fl & 63;
        int s = f >> 2;
        int ot = f & 3;
        const float* Wl = (set == 0) ? Wl0 : (set == 1) ? Wl1 : Wl2;
        const float* Wr = (set == 0) ? Wr0 : (set == 1) ? Wr1 : Wr2;
        int o = ot * 16 + (l & 15);
        int k0 = s * 32 + (l >> 4) * 8;
        unsigned d[4];
#pragma unroll
        for (int p = 0; p < 4; ++p) {
            int ka = k0 + 2 * p, kb = k0 + 2 * p + 1;
            float va = (ka < 64) ? Wl[o * 64 + ka] : Wr[o * 64 + (ka - 64)];
            float vb = (kb < 64) ? Wl[o * 64 + kb] : Wr[o * 64 + (kb - 64)];
            d[p] = (unsigned)f2b(va) | ((unsigned)f2b(vb) << 16);
        }
        ((uint4*)wbuf)[g] = make_uint4(d[0], d[1], d[2], d[3]);
    } else if (b < 12 + NB1) {
        int tb = b - 12;              // tile index
        for (int i = t; i < nf; i += 256) h[i] = 0;
        __syncthreads();
        int base = tb * TILE1;
        int end = min(base + TILE1, E);
        const int4* d4 = (const int4*)dst;
        int n4 = (end - base) >> 2;
        int b4 = base >> 2;
        for (int k = t; k < n4; k += 256) {
            int4 v = d4[b4 + k];
            atomicAdd(&h[v.x >> 7], 1);
            atomicAdd(&h[v.y >> 7], 1);
            atomicAdd(&h[v.z >> 7], 1);
            atomicAdd(&h[v.w >> 7], 1);
        }
        __syncthreads();
        for (int i = t; i < nf; i += 256) binMat[i * NB1 + tb] = h[i];
    } else {
        int i = (b - 12 - NB1) * 256 + t;   // float4 index
        int n4 = nElem >> 2;
        if (i < n4) {
            float4 v = ((const float4*)x)[i];
            uint2 o;
            o.x = (unsigned)f2b(v.x) | ((unsigned)f2b(v.y) << 16);
            o.y = (unsigned)f2b(v.z) | ((unsigned)f2b(v.w) << 16);
            ((uint2*)xb)[i] = o;
        }
    }
}

// ---------------------------------------------------------------------------
// Scan level 1: per-1024-chunk exclusive scan (in-place) + RAW chunk sums.
// Consumers (scatter/phase2) scan the <=256 chunk sums inline in LDS:
//   full_excl[j] = binMat[j] + excl_scan(blockSums)[j >> 10]
// ---------------------------------------------------------------------------
__global__ __launch_bounds__(SCAN_BLK) void scan_blocks_kernel(
    int* __restrict__ a, int* __restrict__ blockSums, int len) {
    __shared__ int sh[SCAN_BLK];
    int t = threadIdx.x;
    int i = blockIdx.x * SCAN_BLK + t;
    int v = (i < len) ? a[i] : 0;
    sh[t] = v;
    __syncthreads();
    for (int off = 1; off < SCAN_BLK; off <<= 1) {
        int add = (t >= off) ? sh[t - off] : 0;
        __syncthreads();
        sh[t] += add;
        __syncthreads();
    }
    int incl = sh[t];
    if (i < len) a[i] = incl - v;
    if (t == SCAN_BLK - 1) blockSums[blockIdx.x] = incl;   // raw chunk total
}

// Inline exclusive scan of raw chunk sums (nbScan <= 256) with 256 threads.
__device__ __forceinline__ void scan_sums_lds(
    const int* __restrict__ blockSums, int nbScan, int* sBS) {
    int t = threadIdx.x;
    int v = (t < nbScan) ? blockSums[t] : 0;
    sBS[t] = v;
    __syncthreads();
    for (int off = 1; off < 256; off <<= 1) {
        int add = (t >= off) ? sBS[t - off] : 0;
        __syncthreads();
        sBS[t] += add;
        __syncthreads();
    }
    int excl = sBS[t] - v;
    __syncthreads();
    sBS[t] = excl;
    __syncthreads();
}

// ---------------------------------------------------------------------------
// Scatter: deterministic placement into fine-bucket-sorted stage2.
// Packed word: (dst & 127) << 17 | src   (needs N <= 131072)
// ---------------------------------------------------------------------------
__global__ __launch_bounds__(256) void scatter_kernel(
    const int* __restrict__ src, const int* __restrict__ dst,
    const int* __restrict__ binMat, const int* __restrict__ blockSums,
    unsigned* __restrict__ stage2, int E, int NB1, int nf, int nbScan) {
    __shared__ int cur[MAXFB];
    __shared__ int sBS[256];
    int t = threadIdx.x;
    scan_sums_lds(blockSums, nbScan, sBS);
    for (int i = t; i < nf; i += 256) {
        int j = i * NB1 + blockIdx.x;
        cur[i] = binMat[j] + sBS[j >> 10];
    }
    __syncthreads();
    int base = blockIdx.x * TILE1;
    int end = min(base + TILE1, E);
    const int4* s4 = (const int4*)src;
    const int4* d4 = (const int4*)dst;
    int n4 = (end - base) >> 2;
    int b4 = base >> 2;
    for (int k = t; k < n4; k += 256) {
        int4 s = s4[b4 + k];
        int4 d = d4[b4 + k];
        int p0 = atomicAdd(&cur[d.x >> 7], 1);
        int p1 = atomicAdd(&cur[d.y >> 7], 1);
        int p2 = atomicAdd(&cur[d.z >> 7], 1);
        int p3 = atomicAdd(&cur[d.w >> 7], 1);
        stage2[p0] = ((unsigned)(d.x & 127) << 17) | (unsigned)s.x;
        stage2[p1] = ((unsigned)(d.y & 127) << 17) | (unsigned)s.y;
        stage2[p2] = ((unsigned)(d.z & 127) << 17) | (unsigned)s.z;
        stage2[p3] = ((unsigned)(d.w & 127) << 17) | (unsigned)s.w;
    }
}

// ---------------------------------------------------------------------------
// Phase 2: one block per fine bucket (128 nodes) -> csrSrc + rowStart + perm.
// perm[b*128 + rank] = local node index, ranked by degree descending.
// ---------------------------------------------------------------------------
__global__ __launch_bounds__(256) void phase2_kernel(
    const unsigned* __restrict__ stage2, const int* __restrict__ binMat,
    const int* __restrict__ blockSums,
    int* __restrict__ csrSrc, int* __restrict__ rowStart,
    int* __restrict__ perm,
    int E, int NB1, int nf, int nbScan) {
    __shared__ int cnt[128];
    __shared__ int pre[129];
    __shared__ int cur[128];
    __shared__ int sBS[256];
    __shared__ int permL[128];
    int b = blockIdx.x;
    int t = threadIdx.x;
    scan_sums_lds(blockSums, nbScan, sBS);
    int j0 = b * NB1;
    int s = binMat[j0] + sBS[j0 >> 10];
    int e2 = E;
    if (b + 1 < nf) {
        int j1 = (b + 1) * NB1;
        e2 = binMat[j1] + sBS[j1 >> 10];
    }
    if (t < 128) cnt[t] = 0;
    __syncthreads();
    for (int i = s + t; i < e2; i += 256)
        atomicAdd(&cnt[(stage2[i] >> 17) & 127], 1);
    __syncthreads();
    if (t < 128) pre[t + 1] = cnt[t];
    if (t == 0) pre[0] = 0;
    // degree rank (stable: desc degree, asc index); cnt[] stays valid
    if (t < 128) {
        int my = cnt[t];
        int r = 0;
        for (int j = 0; j < 128; ++j) {
            int cj = cnt[j];
            r += (cj > my) || (cj == my && j < t);
        }
        permL[r] = t;
    }
    __syncthreads();
    for (int off = 1; off < 128; off <<= 1) {
        int v = 0;
        if (t < 128 && (t + 1) > off) v = pre[t + 1 - off];
        __syncthreads();
        if (t < 128 && (t + 1) > off) pre[t + 1] += v;
        __syncthreads();
    }
    if (t < 128) cur[t] = pre[t];
    if (t < 129) rowStart[b * 128 + t] = s + pre[t];
    if (t < 128) perm[b * 128 + t] = permL[t];
    __syncthreads();
    for (int i = s + t; i < e2; i += 256) {
        unsigned w = stage2[i];
        int pos = atomicAdd(&cur[(w >> 17) & 127], 1);
        csrSrc[s + pos] = (int)(w & 0x1FFFFu);
    }
}

// ---------------------------------------------------------------------------
// Fused layer (round-7 proven version; 512 threads = 8 waves per tile):
//   Stage:   bucket's contiguous csrSrc slice -> LDS eidx (coalesced, 8 KB).
//   Phase A: gather, 8 lanes/node, 2 nodes/thread, degree-balanced
//            heavy+light team pairing via perm. csrSrc accumulation order
//            unchanged => bit-identical output.
//   Phase B: MFMA matvec, each wave owns one 16-node m-tile
//   Epilogue: tanh + transpose via reused LDS, two 64-row halves.
// flags: bit0 = tanh, bit1 = bf16 output.
// ---------------------------------------------------------------------------
__global__ __launch_bounds__(512, 4) void fused_layer(
    const ushort* __restrict__ hb, const int* __restrict__ rowStart,
    const int* __restrict__ csrSrc, const int* __restrict__ perm,
    const ushort* __restrict__ wbuf,
    const float* __restrict__ bl, void* __restrict__ out, int n, int flags) {
    __shared__ __align__(16) ushort smem[128 * 72];
    __shared__ int eidx[ECAP];

    int t = threadIdx.x;
    int node0b = blockIdx.x * 128;
    const uint4* h16 = (const uint4*)hb;

    // ---- Stage: bucket edge indices -> LDS (coalesced) ----
    int e0 = rowStart[node0b];
    int ne = rowStart[node0b + 128] - e0;
    bool useL = (ne <= ECAP);
    if (useL) {
        for (int i = t; i < ne; i += 512) eidx[i] = csrSrc[e0 + i];
    }
    __syncthreads();

    // ---- Phase A: gather into LDS ----
    {
        int c = t & 7;                 // 16B feature chunk
        int tm = t >> 3;               // team 0..63
        const int* permB = perm + blockIdx.x * 128;
        int nl0 = permB[tm];           // heavy node
        int nl1 = permB[127 - tm];     // light node

        auto run = [&](auto IDX) {
#pragma unroll 1
            for (int r = 0; r < 2; ++r) {
                int nl = (r == 0) ? nl0 : nl1;
                int node = node0b + nl;
                float a[8] = {0.f, 0.f, 0.f, 0.f, 0.f, 0.f, 0.f, 0.f};
                int e = rowStart[node];
                int end = rowStart[node + 1];
                for (; e + 3 < end; e += 4) {
                    int s0 = IDX(e + 0);
                    int s1 = IDX(e + 1);
                    int s2 = IDX(e + 2);
                    int s3 = IDX(e + 3);
                    uint4 u0 = h16[(size_t)s0 * 8 + c];
                    uint4 u1 = h16[(size_t)s1 * 8 + c];
                    uint4 u2 = h16[(size_t)s2 * 8 + c];
                    uint4 u3 = h16[(size_t)s3 * 8 + c];
                    add8(a, u0); add8(a, u1); add8(a, u2); add8(a, u3);
                }
                for (; e < end; ++e) {
                    uint4 u0 = h16[(size_t)IDX(e) * 8 + c];
                    add8(a, u0);
                }
                unsigned d[4];
#pragma unroll
                for (int p = 0; p < 4; ++p)
                    d[p] = (unsigned)f2b(a[2 * p]) | ((unsigned)f2b(a[2 * p + 1]) << 16);
                *(uint4*)(smem + nl * 72 + c * 8) = make_uint4(d[0], d[1], d[2], d[3]);
            }
        };
        if (useL) run([&](int e) { return eidx[e - e0]; });
        else      run([&](int e) { return csrSrc[e]; });
    }
    __syncthreads();

    // ---- Phase B: MFMA matvec (A from LDS for agg, global for self) ----
    int w = t >> 6;                    // wave 0..7 -> 16-node m-tile
    int l = t & 63;
    int quad = l >> 4;
    int lo = l & 15;

    f32x4 acc[4];
#pragma unroll
    for (int ot = 0; ot < 4; ++ot) {
        float bv = bl[ot * 16 + lo];
        f32x4 bvv = {bv, bv, bv, bv};
        acc[ot] = bvv;
    }

#pragma unroll
    for (int s = 0; s < 4; ++s) {
        bf16x8 A;
        if (s < 2) {
            int nl = w * 16 + lo;
            A = *(const bf16x8*)(smem + nl * 72 + s * 32 + quad * 8);
        } else {
            size_t node = (size_t)node0b + w * 16 + lo;
            A = *(const bf16x8*)(hb + node * 64 + (s & 1) * 32 + quad * 8);
        }
#pragma unroll
        for (int ot = 0; ot < 4; ++ot) {
            bf16x8 B = *(const bf16x8*)(wbuf + (((s * 4 + ot) * 64) + l) * 8);
            acc[ot] = __builtin_amdgcn_mfma_f32_16x16x32_bf16(A, B, acc[ot], 0, 0, 0);
        }
    }
    __syncthreads();               // all aggL reads done; smem becomes outT

    // ---- Epilogue: tanh + transpose via LDS, two 64-row halves ----
    float* outT = (float*)smem;
    int whalf = w >> 2;            // which half this wave's rows belong to
    int wrow = (w & 3) * 16;       // row base within the half

#pragma unroll
    for (int half = 0; half < 2; ++half) {
        if (whalf == half) {
#pragma unroll
            for (int ot = 0; ot < 4; ++ot) {
                f32x4 v = acc[ot];
                if (flags & 1) {
                    v[0] = tanhf(v[0]); v[1] = tanhf(v[1]);
                    v[2] = tanhf(v[2]); v[3] = tanhf(v[3]);
                }
                int row = wrow + quad * 4;
                int col = ot * 16 + lo;
#pragma unroll
                for (int r = 0; r < 4; ++r)
                    outT[(row + r) * 68 + col] = v[r];
            }
        }
        __syncthreads();
        // cooperative store of this half's 64 rows: 8 lanes/row x 8 cols
        int hr = t >> 3;
        int node = node0b + half * 64 + hr;
        if (node < n) {
            const float* srcp = &outT[hr * 68 + (t & 7) * 8];
            if (flags & 2) {
                uint4* o8 = (uint4*)out;     // bf16 row = 8 uint4
                unsigned dd[4];
#pragma unroll
                for (int p = 0; p < 4; ++p) {
                    float va = srcp[2 * p];
                    float vb = srcp[2 * p + 1];
                    dd[p] = (unsigned)f2b(va) | ((unsigned)f2b(vb) << 16);
                }
                o8[(size_t)node * 8 + (t & 7)] = make_uint4(dd[0], dd[1], dd[2], dd[3]);
            } else {
                float4* o16 = (float4*)out;  // fp32 row = 16 float4
#pragma unroll
                for (int q = 0; q < 2; ++q) {
                    float4 v = *(const float4*)(srcp + q * 4);
                    o16[(size_t)node * 16 + (t & 7) * 2 + q] = v;
                }
            }
        }
        if (half == 0) __syncthreads();      // protect outT before half-1 writes
    }
}

// ---------------------------------------------------------------------------
// Launch
// ---------------------------------------------------------------------------
extern "C" void kernel_launch(void* const* d_in, const int* in_sizes, int n_in,
                              void* d_out, int out_size, void* d_ws, size_t ws_size,
                              hipStream_t stream) {
    const float* x      = (const float*)d_in[0];
    const int*   edges  = (const int*)d_in[1];
    const float* Wl_in  = (const float*)d_in[2];
    const float* bl_in  = (const float*)d_in[3];
    const float* Wr_in  = (const float*)d_in[4];
    const float* Wl_med = (const float*)d_in[5];
    const float* bl_med = (const float*)d_in[6];
    const float* Wr_med = (const float*)d_in[7];
    const float* Wl_out = (const float*)d_in[8];
    const float* bl_out = (const float*)d_in[9];
    const float* Wr_out = (const float*)d_in[10];

    const int N = in_sizes[0] / F;
    const int E = in_sizes[1] / 2;
    const int* src = edges;
    const int* dst = edges + E;

    const int nf  = (N + 127) >> 7;              // fine buckets (782)
    const int NB1 = (E + TILE1 - 1) / TILE1;     // bucketing tiles (293)
    const int NR  = nf * 128;                    // padded node count
    const int scanLen = nf * NB1;                // 229K
    const int nbScan = (scanLen + SCAN_BLK - 1) / SCAN_BLK;   // 224 (<= 256)

    // Workspace layout (16B-aligned chunks)
    ushort*  wbuf      = (ushort*)d_ws;                        // 3*8192 bf16
    ushort*  xb        = wbuf + 3 * 8192;                      // NR*F bf16
    ushort*  hAb       = xb + (size_t)NR * F;                  // NR*F bf16
    ushort*  hBb       = hAb + (size_t)NR * F;                 // NR*F bf16
    int*     rowStart  = (int*)(hBb + (size_t)NR * F);         // NR+2
    int*     blockSums = rowStart + NR + 2;                    // nbScan (<=1024)
    int*     binMat    = blockSums + SCAN_BLK;                 // nf*NB1
    unsigned* stage2   = (unsigned*)(binMat + scanLen);        // E
    int*     csrSrc    = (int*)(stage2 + E);                   // E
    int*     perm      = csrSrc + E;                           // NR

    const int prep_blocks = 12 + NB1 + (N * F / 4 + 255) / 256;

    // Preprocessing: prep+hist merged, chunk scan, scatter, phase2
    prep_hist_kernel<<<prep_blocks, 256, 0, stream>>>(
        Wl_in, Wr_in, Wl_med, Wr_med, Wl_out, Wr_out, wbuf, x, xb, N * F,
        dst, binMat, E, NB1, nf);
    scan_blocks_kernel<<<nbScan, SCAN_BLK, 0, stream>>>(binMat, blockSums, scanLen);
    scatter_kernel<<<NB1, 256, 0, stream>>>(src, dst, binMat, blockSums, stage2, E, NB1, nf, nbScan);
    phase2_kernel<<<nf, 256, 0, stream>>>(stage2, binMat, blockSums, csrSrc, rowStart, perm, E, NB1, nf, nbScan);

    // Fused layers: gather + MFMA matvec in one kernel per layer
    fused_layer<<<nf, 512, 0, stream>>>(xb,  rowStart, csrSrc, perm, wbuf,         bl_in,  hAb,   N, 3);
    fused_layer<<<nf, 512, 0, stream>>>(hAb, rowStart, csrSrc, perm, wbuf + 8192,  bl_med, hBb,   N, 3);
    fused_layer<<<nf, 512, 0, stream>>>(hBb, rowStart, csrSrc, perm, wbuf + 8192,  bl_med, hAb,   N, 3);
    fused_layer<<<nf, 512, 0, stream>>>(hAb, rowStart, csrSrc, perm, wbuf + 16384, bl_out, d_out, N, 0);
}

// Round 12
// 255.888 us; speedup vs baseline: 2.8798x; 1.0255x over previous
//
#include <hip/hip_runtime.h>
#include <cstdint>

#define F 64
#define TILE1 8192     // edges per bucketing tile
#define MAXFB 1024     // max fine buckets (supports N <= 131072)
#define SCAN_BLK 1024  // elements per scan chunk (nbScan must stay <= 256)
#define ECAP 2048      // staged edge capacity per bucket (mean 1536, 13 sigma)

typedef short bf16x8 __attribute__((ext_vector_type(8)));
typedef float f32x4  __attribute__((ext_vector_type(4)));

// ---------------------------------------------------------------------------
// bf16 helpers
// ---------------------------------------------------------------------------
__device__ __forceinline__ unsigned short f2b(float f) {     // RNE round
    unsigned u = __float_as_uint(f);
    unsigned r = u + 0x7fffu + ((u >> 16) & 1u);
    return (unsigned short)(r >> 16);
}
__device__ __forceinline__ void add8(float* a, uint4 u) {
    const unsigned* p = (const unsigned*)&u;
#pragma unroll
    for (int i = 0; i < 4; ++i) {
        a[2 * i + 0] += __uint_as_float(p[i] << 16);
        a[2 * i + 1] += __uint_as_float(p[i] & 0xffff0000u);
    }
}

// ---------------------------------------------------------------------------
// Merged prep + hist:
//   blocks [0,12)           : weight B-fragments -> wbuf
//   blocks [12, 12+NB1)     : per-tile histogram by fine bucket (LDS atomics)
//   blocks [12+NB1, ...)    : x -> bf16
// ---------------------------------------------------------------------------
__global__ __launch_bounds__(256) void prep_hist_kernel(
    const float* __restrict__ Wl0, const float* __restrict__ Wr0,
    const float* __restrict__ Wl1, const float* __restrict__ Wr1,
    const float* __restrict__ Wl2, const float* __restrict__ Wr2,
    ushort* __restrict__ wbuf,
    const float* __restrict__ x, ushort* __restrict__ xb, int nElem,
    const int* __restrict__ dst, int* __restrict__ binMat,
    int E, int NB1, int nf) {
    __shared__ int h[MAXFB];
    int b = blockIdx.x;
    int t = threadIdx.x;
    if (b < 12) {
        int g = b * 256 + t;          // g < 3072 = 3 sets * 16 frags * 64 lanes
        int set = g >> 10;
        int fl = g & 1023;
        int f = fl >> 6;              // frag id = s*4+ot
        int l = fl & 63;
        int s = f >> 2;
        int ot = f & 3;
        const float* Wl = (set == 0) ? Wl0 : (set == 1) ? Wl1 : Wl2;
        const float* Wr = (set == 0) ? Wr0 : (set == 1) ? Wr1 : Wr2;
        int o = ot * 16 + (l & 15);
        int k0 = s * 32 + (l >> 4) * 8;
        unsigned d[4];
#pragma unroll
        for (int p = 0; p < 4; ++p) {
            int ka = k0 + 2 * p, kb = k0 + 2 * p + 1;
            float va = (ka < 64) ? Wl[o * 64 + ka] : Wr[o * 64 + (ka - 64)];
            float vb = (kb < 64) ? Wl[o * 64 + kb] : Wr[o * 64 + (kb - 64)];
            d[p] = (unsigned)f2b(va) | ((unsigned)f2b(vb) << 16);
        }
        ((uint4*)wbuf)[g] = make_uint4(d[0], d[1], d[2], d[3]);
    } else if (b < 12 + NB1) {
        int tb = b - 12;              // tile index
        for (int i = t; i < nf; i += 256) h[i] = 0;
        __syncthreads();
        int base = tb * TILE1;
        int end = min(base + TILE1, E);
        const int4* d4 = (const int4*)dst;
        int n4 = (end - base) >> 2;
        int b4 = base >> 2;
        for (int k = t; k < n4; k += 256) {
            int4 v = d4[b4 + k];
            atomicAdd(&h[v.x >> 7], 1);
            atomicAdd(&h[v.y >> 7], 1);
            atomicAdd(&h[v.z >> 7], 1);
            atomicAdd(&h[v.w >> 7], 1);
        }
        __syncthreads();
        for (int i = t; i < nf; i += 256) binMat[i * NB1 + tb] = h[i];
    } else {
        int i = (b - 12 - NB1) * 256 + t;   // float4 index
        int n4 = nElem >> 2;
        if (i < n4) {
            float4 v = ((const float4*)x)[i];
            uint2 o;
            o.x = (unsigned)f2b(v.x) | ((unsigned)f2b(v.y) << 16);
            o.y = (unsigned)f2b(v.z) | ((unsigned)f2b(v.w) << 16);
            ((uint2*)xb)[i] = o;
        }
    }
}

// ---------------------------------------------------------------------------
// Scan level 1: per-1024-chunk exclusive scan (in-place) + RAW chunk sums.
// Consumers (scatter/phase2) scan the <=256 chunk sums inline in LDS:
//   full_excl[j] = binMat[j] + excl_scan(blockSums)[j >> 10]
// ---------------------------------------------------------------------------
__global__ __launch_bounds__(SCAN_BLK) void scan_blocks_kernel(
    int* __restrict__ a, int* __restrict__ blockSums, int len) {
    __shared__ int sh[SCAN_BLK];
    int t = threadIdx.x;
    int i = blockIdx.x * SCAN_BLK + t;
    int v = (i < len) ? a[i] : 0;
    sh[t] = v;
    __syncthreads();
    for (int off = 1; off < SCAN_BLK; off <<= 1) {
        int add = (t >= off) ? sh[t - off] : 0;
        __syncthreads();
        sh[t] += add;
        __syncthreads();
    }
    int incl = sh[t];
    if (i < len) a[i] = incl - v;
    if (t == SCAN_BLK - 1) blockSums[blockIdx.x] = incl;   // raw chunk total
}

// Inline exclusive scan of raw chunk sums (nbScan <= 256) with 256 threads.
__device__ __forceinline__ void scan_sums_lds(
    const int* __restrict__ blockSums, int nbScan, int* sBS) {
    int t = threadIdx.x;
    int v = (t < nbScan) ? blockSums[t] : 0;
    sBS[t] = v;
    __syncthreads();
    for (int off = 1; off < 256; off <<= 1) {
        int add = (t >= off) ? sBS[t - off] : 0;
        __syncthreads();
        sBS[t] += add;
        __syncthreads();
    }
    int excl = sBS[t] - v;
    __syncthreads();
    sBS[t] = excl;
    __syncthreads();
}

// ---------------------------------------------------------------------------
// Scatter: deterministic placement into fine-bucket-sorted stage2.
// Packed word: (dst & 127) << 17 | src   (needs N <= 131072)
// ---------------------------------------------------------------------------
__global__ __launch_bounds__(256) void scatter_kernel(
    const int* __restrict__ src, const int* __restrict__ dst,
    const int* __restrict__ binMat, const int* __restrict__ blockSums,
    unsigned* __restrict__ stage2, int E, int NB1, int nf, int nbScan) {
    __shared__ int cur[MAXFB];
    __shared__ int sBS[256];
    int t = threadIdx.x;
    scan_sums_lds(blockSums, nbScan, sBS);
    for (int i = t; i < nf; i += 256) {
        int j = i * NB1 + blockIdx.x;
        cur[i] = binMat[j] + sBS[j >> 10];
    }
    __syncthreads();
    int base = blockIdx.x * TILE1;
    int end = min(base + TILE1, E);
    const int4* s4 = (const int4*)src;
    const int4* d4 = (const int4*)dst;
    int n4 = (end - base) >> 2;
    int b4 = base >> 2;
    for (int k = t; k < n4; k += 256) {
        int4 s = s4[b4 + k];
        int4 d = d4[b4 + k];
        int p0 = atomicAdd(&cur[d.x >> 7], 1);
        int p1 = atomicAdd(&cur[d.y >> 7], 1);
        int p2 = atomicAdd(&cur[d.z >> 7], 1);
        int p3 = atomicAdd(&cur[d.w >> 7], 1);
        stage2[p0] = ((unsigned)(d.x & 127) << 17) | (unsigned)s.x;
        stage2[p1] = ((unsigned)(d.y & 127) << 17) | (unsigned)s.y;
        stage2[p2] = ((unsigned)(d.z & 127) << 17) | (unsigned)s.z;
        stage2[p3] = ((unsigned)(d.w & 127) << 17) | (unsigned)s.w;
    }
}

// ---------------------------------------------------------------------------
// Phase 2: one block per fine bucket (128 nodes) -> csrSrc + rowStart + perm.
// perm[b*128 + rank] = local node index, ranked by degree descending.
// ---------------------------------------------------------------------------
__global__ __launch_bounds__(256) void phase2_kernel(
    const unsigned* __restrict__ stage2, const int* __restrict__ binMat,
    const int* __restrict__ blockSums,
    int* __restrict__ csrSrc, int* __restrict__ rowStart,
    int* __restrict__ perm,
    int E, int NB1, int nf, int nbScan) {
    __shared__ int cnt[128];
    __shared__ int pre[129];
    __shared__ int cur[128];
    __shared__ int sBS[256];
    __shared__ int permL[128];
    int b = blockIdx.x;
    int t = threadIdx.x;
    scan_sums_lds(blockSums, nbScan, sBS);
    int j0 = b * NB1;
    int s = binMat[j0] + sBS[j0 >> 10];
    int e2 = E;
    if (b + 1 < nf) {
        int j1 = (b + 1) * NB1;
        e2 = binMat[j1] + sBS[j1 >> 10];
    }
    if (t < 128) cnt[t] = 0;
    __syncthreads();
    for (int i = s + t; i < e2; i += 256)
        atomicAdd(&cnt[(stage2[i] >> 17) & 127], 1);
    __syncthreads();
    if (t < 128) pre[t + 1] = cnt[t];
    if (t == 0) pre[0] = 0;
    // degree rank (stable: desc degree, asc index); cnt[] stays valid
    if (t < 128) {
        int my = cnt[t];
        int r = 0;
        for (int j = 0; j < 128; ++j) {
            int cj = cnt[j];
            r += (cj > my) || (cj == my && j < t);
        }
        permL[r] = t;
    }
    __syncthreads();
    for (int off = 1; off < 128; off <<= 1) {
        int v = 0;
        if (t < 128 && (t + 1) > off) v = pre[t + 1 - off];
        __syncthreads();
        if (t < 128 && (t + 1) > off) pre[t + 1] += v;
        __syncthreads();
    }
    if (t < 128) cur[t] = pre[t];
    if (t < 129) rowStart[b * 128 + t] = s + pre[t];
    if (t < 128) perm[b * 128 + t] = permL[t];
    __syncthreads();
    for (int i = s + t; i < e2; i += 256) {
        unsigned w = stage2[i];
        int pos = atomicAdd(&cur[(w >> 17) & 127], 1);
        csrSrc[s + pos] = (int)(w & 0x1FFFFu);
    }
}

// ---------------------------------------------------------------------------
// Fused layer (512 threads = 8 waves per 128-node tile):
//   Stage:   bucket's contiguous csrSrc slice -> LDS eidx (coalesced, 8 KB).
//   Phase A: gather, 8 lanes/node, 2 nodes/thread, degree-balanced
//            heavy+light team pairing via perm. csrSrc accumulation order
//            unchanged => bit-identical output.
//   Phase B: MFMA matvec, each wave owns one 16-node m-tile
//   Epilogue: tanh + transpose via reused LDS, two 64-row halves.
// flags: bit0 = tanh, bit1 = bf16 output.
// ---------------------------------------------------------------------------
__global__ __launch_bounds__(512, 4) void fused_layer(
    const ushort* __restrict__ hb, const int* __restrict__ rowStart,
    const int* __restrict__ csrSrc, const int* __restrict__ perm,
    const ushort* __restrict__ wbuf,
    const float* __restrict__ bl, void* __restrict__ out, int n, int flags) {
    __shared__ __align__(16) ushort smem[128 * 72];
    __shared__ int eidx[ECAP];

    int t = threadIdx.x;
    int node0b = blockIdx.x * 128;
    const uint4* h16 = (const uint4*)hb;

    // ---- Stage: bucket edge indices -> LDS (coalesced) ----
    int e0 = rowStart[node0b];
    int ne = rowStart[node0b + 128] - e0;
    bool useL = (ne <= ECAP);
    if (useL) {
        for (int i = t; i < ne; i += 512) eidx[i] = csrSrc[e0 + i];
    }
    __syncthreads();

    // ---- Phase A: gather into LDS ----
    {
        int c = t & 7;                 // 16B feature chunk
        int tm = t >> 3;               // team 0..63
        const int* permB = perm + blockIdx.x * 128;
        int nl0 = permB[tm];           // heavy node
        int nl1 = permB[127 - tm];     // light node

        auto run = [&](auto IDX) {
#pragma unroll 1
            for (int r = 0; r < 2; ++r) {
                int nl = (r == 0) ? nl0 : nl1;
                int node = node0b + nl;
                float a[8] = {0.f, 0.f, 0.f, 0.f, 0.f, 0.f, 0.f, 0.f};
                int e = rowStart[node];
                int end = rowStart[node + 1];
                for (; e + 3 < end; e += 4) {
                    int s0 = IDX(e + 0);
                    int s1 = IDX(e + 1);
                    int s2 = IDX(e + 2);
                    int s3 = IDX(e + 3);
                    uint4 u0 = h16[(size_t)s0 * 8 + c];
                    uint4 u1 = h16[(size_t)s1 * 8 + c];
                    uint4 u2 = h16[(size_t)s2 * 8 + c];
                    uint4 u3 = h16[(size_t)s3 * 8 + c];
                    add8(a, u0); add8(a, u1); add8(a, u2); add8(a, u3);
                }
                for (; e < end; ++e) {
                    uint4 u0 = h16[(size_t)IDX(e) * 8 + c];
                    add8(a, u0);
                }
                unsigned d[4];
#pragma unroll
                for (int p = 0; p < 4; ++p)
                    d[p] = (unsigned)f2b(a[2 * p]) | ((unsigned)f2b(a[2 * p + 1]) << 16);
                *(uint4*)(smem + nl * 72 + c * 8) = make_uint4(d[0], d[1], d[2], d[3]);
            }
        };
        if (useL) run([&](int e) { return eidx[e - e0]; });
        else      run([&](int e) { return csrSrc[e]; });
    }
    __syncthreads();

    // ---- Phase B: MFMA matvec (A from LDS for agg, global for self) ----
    int w = t >> 6;                    // wave 0..7 -> 16-node m-tile
    int l = t & 63;
    int quad = l >> 4;
    int lo = l & 15;

    f32x4 acc[4];
#pragma unroll
    for (int ot = 0; ot < 4; ++ot) {
        float bv = bl[ot * 16 + lo];
        f32x4 bvv = {bv, bv, bv, bv};
        acc[ot] = bvv;
    }

#pragma unroll
    for (int s = 0; s < 4; ++s) {
        bf16x8 A;
        if (s < 2) {
            int nl = w * 16 + lo;
            A = *(const bf16x8*)(smem + nl * 72 + s * 32 + quad * 8);
        } else {
            size_t node = (size_t)node0b + w * 16 + lo;
            A = *(const bf16x8*)(hb + node * 64 + (s & 1) * 32 + quad * 8);
        }
#pragma unroll
        for (int ot = 0; ot < 4; ++ot) {
            bf16x8 B = *(const bf16x8*)(wbuf + (((s * 4 + ot) * 64) + l) * 8);
            acc[ot] = __builtin_amdgcn_mfma_f32_16x16x32_bf16(A, B, acc[ot], 0, 0, 0);
        }
    }
    __syncthreads();               // all aggL reads done; smem becomes outT

    // ---- Epilogue: tanh + transpose via LDS, two 64-row halves ----
    float* outT = (float*)smem;
    int whalf = w >> 2;            // which half this wave's rows belong to
    int wrow = (w & 3) * 16;       // row base within the half

#pragma unroll
    for (int half = 0; half < 2; ++half) {
        if (whalf == half) {
#pragma unroll
            for (int ot = 0; ot < 4; ++ot) {
                f32x4 v = acc[ot];
                if (flags & 1) {
                    v[0] = tanhf(v[0]); v[1] = tanhf(v[1]);
                    v[2] = tanhf(v[2]); v[3] = tanhf(v[3]);
                }
                int row = wrow + quad * 4;
                int col = ot * 16 + lo;
#pragma unroll
                for (int r = 0; r < 4; ++r)
                    outT[(row + r) * 68 + col] = v[r];
            }
        }
        __syncthreads();
        // cooperative store of this half's 64 rows: 8 lanes/row x 8 cols
        int hr = t >> 3;
        int node = node0b + half * 64 + hr;
        if (node < n) {
            const float* srcp = &outT[hr * 68 + (t & 7) * 8];
            if (flags & 2) {
                uint4* o8 = (uint4*)out;     // bf16 row = 8 uint4
                unsigned dd[4];
#pragma unroll
                for (int p = 0; p < 4; ++p) {
                    float va = srcp[2 * p];
                    float vb = srcp[2 * p + 1];
                    dd[p] = (unsigned)f2b(va) | ((unsigned)f2b(vb) << 16);
                }
                o8[(size_t)node * 8 + (t & 7)] = make_uint4(dd[0], dd[1], dd[2], dd[3]);
            } else {
                float4* o16 = (float4*)out;  // fp32 row = 16 float4
#pragma unroll
                for (int q = 0; q < 2; ++q) {
                    float4 v = *(const float4*)(srcp + q * 4);
                    o16[(size_t)node * 16 + (t & 7) * 2 + q] = v;
                }
            }
        }
        if (half == 0) __syncthreads();      // protect outT before half-1 writes
    }
}

// ---------------------------------------------------------------------------
// Launch
// ---------------------------------------------------------------------------
extern "C" void kernel_launch(void* const* d_in, const int* in_sizes, int n_in,
                              void* d_out, int out_size, void* d_ws, size_t ws_size,
                              hipStream_t stream) {
    const float* x      = (const float*)d_in[0];
    const int*   edges  = (const int*)d_in[1];
    const float* Wl_in  = (const float*)d_in[2];
    const float* bl_in  = (const float*)d_in[3];
    const float* Wr_in  = (const float*)d_in[4];
    const float* Wl_med = (const float*)d_in[5];
    const float* bl_med = (const float*)d_in[6];
    const float* Wr_med = (const float*)d_in[7];
    const float* Wl_out = (const float*)d_in[8];
    const float* bl_out = (const float*)d_in[9];
    const float* Wr_out = (const float*)d_in[10];

    const int N = in_sizes[0] / F;
    const int E = in_sizes[1] / 2;
    const int* src = edges;
    const int* dst = edges + E;

    const int nf  = (N + 127) >> 7;              // fine buckets (782)
    const int NB1 = (E + TILE1 - 1) / TILE1;     // bucketing tiles (147)
    const int NR  = nf * 128;                    // padded node count
    const int scanLen = nf * NB1;
    const int nbScan = (scanLen + SCAN_BLK - 1) / SCAN_BLK;   // 113 (<= 256)

    // Workspace layout (16B-aligned chunks)
    ushort*  wbuf      = (ushort*)d_ws;                        // 3*8192 bf16
    ushort*  xb        = wbuf + 3 * 8192;                      // NR*F bf16
    ushort*  hAb       = xb + (size_t)NR * F;                  // NR*F bf16
    ushort*  hBb       = hAb + (size_t)NR * F;                 // NR*F bf16
    int*     rowStart  = (int*)(hBb + (size_t)NR * F);         // NR+2
    int*     blockSums = rowStart + NR + 2;                    // nbScan (<=1024)
    int*     binMat    = blockSums + SCAN_BLK;                 // nf*NB1
    unsigned* stage2   = (unsigned*)(binMat + scanLen);        // E
    int*     csrSrc    = (int*)(stage2 + E);                   // E
    int*     perm      = csrSrc + E;                           // NR

    const int prep_blocks = 12 + NB1 + (N * F / 4 + 255) / 256;

    // Preprocessing: prep+hist merged, chunk scan, scatter, phase2
    prep_hist_kernel<<<prep_blocks, 256, 0, stream>>>(
        Wl_in, Wr_in, Wl_med, Wr_med, Wl_out, Wr_out, wbuf, x, xb, N * F,
        dst, binMat, E, NB1, nf);
    scan_blocks_kernel<<<nbScan, SCAN_BLK, 0, stream>>>(binMat, blockSums, scanLen);
    scatter_kernel<<<NB1, 256, 0, stream>>>(src, dst, binMat, blockSums, stage2, E, NB1, nf, nbScan);
    phase2_kernel<<<nf, 256, 0, stream>>>(stage2, binMat, blockSums, csrSrc, rowStart, perm, E, NB1, nf, nbScan);

    // Fused layers: gather + MFMA matvec in one kernel per layer
    fused_layer<<<nf, 512, 0, stream>>>(xb,  rowStart, csrSrc, perm, wbuf,         bl_in,  hAb,   N, 3);
    fused_layer<<<nf, 512, 0, stream>>>(hAb, rowStart, csrSrc, perm, wbuf + 8192,  bl_med, hBb,   N, 3);
    fused_layer<<<nf, 512, 0, stream>>>(hBb, rowStart, csrSrc, perm, wbuf + 8192,  bl_med, hAb,   N, 3);
    fused_layer<<<nf, 512, 0, stream>>>(hAb, rowStart, csrSrc, perm, wbuf + 16384, bl_out, d_out, N, 0);
}